// Round 2
// baseline (1215.209 us; speedup 1.0000x reference)
//
#include <hip/hip_runtime.h>
#include <cstdint>

#define NSI   100000
#define NM    100000
#define NINT  500000
#define NEDGE 500000
#define NB_SCAN 489   // ceil(NINT/1024)

// ---------------- workspace layout (float offsets) ----------------
static const long OFF_WSI  = 0;                       // [128][64] cat: cols 0-31 W1l_si2i, 32-63 W1l_si+W1r_si
static const long OFF_WM   = 8192;                    // [128][64] same for m
static const long OFF_WIT  = 16384;                   // [32][64] transposed 0.5*(W1r_si2i+W1r_m2i)
static const long OFF_BI   = 18432;                   // [32] 0.5*(b1_si2i+b1_m2i)
static const long OFF_USI  = 18464;                   // [32] W2l_si2i @ wlin
static const long OFF_UM   = 18496;                   // [32]
static const long OFF_V    = 18528;                   // [32] 0.5*(W2r_si2i+W2r_m2i) @ wlin
static const long OFF_C0   = 18560;                   // [1] scalar bias (pad 32)
static const long OFF_PSI  = 18592;                   // [NSI][32] x_si @ W1l_si2i
static const long OFF_HSI  = OFF_PSI + 3200000;       // [NSI][32] relu(x_si@(W1l+W1r)+b)
static const long OFF_PM   = OFF_HSI + 3200000;
static const long OFF_HM   = OFF_PM + 3200000;
static const long OFF_SSI  = OFF_HM + 3200000;        // [NSI] layer2 scalar per src node
static const long OFF_SM   = OFF_SSI + 100000;
// int region (cast to int*)
static const long OFF_DEG  = OFF_SM + 100000;         // deg_si, deg_m, cur_si, cur_m (4x500K, ZEROED)
static const long OFF_RP   = OFF_DEG + 2000000;       // rp_si, rp_m
static const long OFF_EI   = OFF_RP + 1000000;        // ei_si, ei_m (src indices bucketed by dst)
static const long OFF_BS   = OFF_EI + 1000000;        // block sums 2x512
static const long OFF_END  = OFF_BS + 1024;           // ~17.0M floats = 68 MB

// ---------------- prep: combined weight tensors ----------------
__global__ __launch_bounds__(256) void prep_kernel(
    const float* __restrict__ W1l_si2i, const float* __restrict__ W1l_si, const float* __restrict__ W1r_si,
    const float* __restrict__ W1l_m2i,  const float* __restrict__ W1l_m,  const float* __restrict__ W1r_m,
    const float* __restrict__ W1r_si2i, const float* __restrict__ W1r_m2i,
    const float* __restrict__ b1_si2i,  const float* __restrict__ b1_m2i,
    const float* __restrict__ W2l_si2i, const float* __restrict__ W2l_m2i,
    const float* __restrict__ W2r_si2i, const float* __restrict__ W2r_m2i,
    const float* __restrict__ b2_si2i,  const float* __restrict__ b2_m2i,
    const float* __restrict__ Wlin,     const float* __restrict__ blin,
    float* __restrict__ Wsi, float* __restrict__ Wm, float* __restrict__ Wit, float* __restrict__ bi,
    float* __restrict__ u_si, float* __restrict__ u_m, float* __restrict__ v, float* __restrict__ c0)
{
    const int tid = threadIdx.x;
    for (int idx = tid; idx < 128 * 64; idx += 256) {
        int k = idx >> 6, c = idx & 63;
        float a, b;
        if (c < 32) { a = W1l_si2i[k * 32 + c];      b = W1l_m2i[k * 32 + c]; }
        else { int cc = c - 32;
               a = W1l_si[k * 32 + cc] + W1r_si[k * 32 + cc];
               b = W1l_m[k * 32 + cc]  + W1r_m[k * 32 + cc]; }
        Wsi[idx] = a; Wm[idx] = b;
    }
    // transposed int-node weight: Wit[c][k] = 0.5*(W1r_si2i[k][c] + W1r_m2i[k][c])
    for (int idx = tid; idx < 32 * 64; idx += 256) {
        int c = idx >> 6, k = idx & 63;
        Wit[idx] = 0.5f * (W1r_si2i[k * 32 + c] + W1r_m2i[k * 32 + c]);
    }
    if (tid < 32) {
        bi[tid] = 0.5f * (b1_si2i[tid] + b1_m2i[tid]);
        float us = 0.f, um = 0.f, vv = 0.f;
        for (int k = 0; k < 16; ++k) {
            float wl = Wlin[k];
            us += W2l_si2i[tid * 16 + k] * wl;
            um += W2l_m2i[tid * 16 + k] * wl;
            vv += 0.5f * (W2r_si2i[tid * 16 + k] + W2r_m2i[tid * 16 + k]) * wl;
        }
        u_si[tid] = us; u_m[tid] = um; v[tid] = vv;
    }
    if (tid == 0) {
        float c = blin[0];
        for (int k = 0; k < 16; ++k) c += 0.5f * (b2_si2i[k] + b2_m2i[k]) * Wlin[k];
        c0[0] = c;
    }
}

// ---------------- GEMM for src node types: K=128, M=64 (P|H), 64-row tile ----------------
__global__ __launch_bounds__(256) void gemm_src(
    const float* __restrict__ X, const float* __restrict__ Wcat, const float* __restrict__ bias,
    float* __restrict__ P, float* __restrict__ H, int N)
{
    __shared__ float xs[64 * 132];
    __shared__ float lw[64 * 64];
    const int tid = threadIdx.x;
    const long row_base = (long)blockIdx.x * 64;

    #pragma unroll
    for (int i = 0; i < 8; ++i) {
        int idx = tid + i * 256;
        int r = idx >> 5, k4 = idx & 31;
        long rr = row_base + r;
        float4 val = make_float4(0.f, 0.f, 0.f, 0.f);
        if (rr < N) val = ((const float4*)X)[rr * 32 + k4];
        *(float4*)&xs[r * 132 + k4 * 4] = val;
    }

    const int r0 = tid & 15;
    const int c0 = (tid >> 4) * 4;
    float acc[4][4] = {{0.f}};

    for (int half = 0; half < 2; ++half) {
        __syncthreads();
        #pragma unroll
        for (int i = 0; i < 4; ++i) {
            int idx = tid + i * 256;
            ((float4*)lw)[idx] = ((const float4*)Wcat)[half * 1024 + idx];
        }
        __syncthreads();
        const float* xb = xs + half * 64;
        #pragma unroll 4
        for (int k = 0; k < 64; k += 4) {
            float4 xr[4];
            #pragma unroll
            for (int j = 0; j < 4; ++j)
                xr[j] = *(const float4*)&xb[(r0 + 16 * j) * 132 + k];
            #pragma unroll
            for (int kk = 0; kk < 4; ++kk) {
                float4 wv = *(const float4*)&lw[(k + kk) * 64 + c0];
                #pragma unroll
                for (int j = 0; j < 4; ++j) {
                    float xv = (kk == 0) ? xr[j].x : (kk == 1) ? xr[j].y : (kk == 2) ? xr[j].z : xr[j].w;
                    acc[j][0] = fmaf(xv, wv.x, acc[j][0]);
                    acc[j][1] = fmaf(xv, wv.y, acc[j][1]);
                    acc[j][2] = fmaf(xv, wv.z, acc[j][2]);
                    acc[j][3] = fmaf(xv, wv.w, acc[j][3]);
                }
            }
        }
    }

    #pragma unroll
    for (int j = 0; j < 4; ++j) {
        long rr = row_base + r0 + 16 * j;
        if (rr >= N) continue;
        if (c0 < 32) {
            *(float4*)&P[rr * 32 + c0] = make_float4(acc[j][0], acc[j][1], acc[j][2], acc[j][3]);
        } else {
            const int cc = c0 - 32;
            float4 o;
            o.x = fmaxf(acc[j][0] + bias[cc + 0], 0.f);
            o.y = fmaxf(acc[j][1] + bias[cc + 1], 0.f);
            o.z = fmaxf(acc[j][2] + bias[cc + 2], 0.f);
            o.w = fmaxf(acc[j][3] + bias[cc + 3], 0.f);
            *(float4*)&H[rr * 32 + cc] = o;
        }
    }
}

// ---------------- per-src-node layer-2 scalar: s[n] = h[n] . u ----------------
__global__ __launch_bounds__(256) void s_kernel(
    const float* __restrict__ h_si, const float* __restrict__ h_m,
    const float* __restrict__ u_si, const float* __restrict__ u_m,
    float* __restrict__ s_si, float* __restrict__ s_m)
{
    long gid = (long)blockIdx.x * 256 + threadIdx.x;
    long node = gid >> 5;
    int f = (int)(gid & 31);
    if (node >= (long)(NSI + NM)) return;
    const float* h; const float* u; float* s; long n;
    if (node < NSI) { h = h_si; u = u_si; s = s_si; n = node; }
    else            { h = h_m;  u = u_m;  s = s_m;  n = node - NSI; }
    float t = h[n * 32 + f] * u[f];
    #pragma unroll
    for (int off = 16; off > 0; off >>= 1) t += __shfl_xor(t, off);
    if (f == 0) s[n] = t;
}

// ---------------- CSR build: histogram ----------------
__global__ __launch_bounds__(256) void hist_kernel(
    const int* __restrict__ dst_si, const int* __restrict__ dst_m,
    int* __restrict__ deg_si, int* __restrict__ deg_m)
{
    int e = blockIdx.x * 256 + threadIdx.x;
    if (e >= NEDGE) return;
    if (blockIdx.y == 0) atomicAdd(&deg_si[dst_si[e]], 1);
    else                 atomicAdd(&deg_m[dst_m[e]], 1);
}

// ---------------- CSR build: block-level exclusive scan (1024 elems/block) ----------------
__global__ __launch_bounds__(256) void scan1_kernel(
    const int* __restrict__ deg_si, const int* __restrict__ deg_m,
    int* __restrict__ rp_si, int* __restrict__ rp_m, int* __restrict__ bsum)
{
    const int rel = blockIdx.y;
    const int* deg = rel ? deg_m : deg_si;
    int* rp = rel ? rp_m : rp_si;
    __shared__ int ls[256];
    const int tid = threadIdx.x;
    const int base = blockIdx.x * 1024 + tid * 4;
    int v[4];
    #pragma unroll
    for (int j = 0; j < 4; ++j) v[j] = (base + j < NINT) ? deg[base + j] : 0;
    int tsum = v[0] + v[1] + v[2] + v[3];
    ls[tid] = tsum;
    __syncthreads();
    for (int off = 1; off < 256; off <<= 1) {
        int t = (tid >= off) ? ls[tid - off] : 0;
        __syncthreads();
        ls[tid] += t;
        __syncthreads();
    }
    int run = ls[tid] - tsum;
    #pragma unroll
    for (int j = 0; j < 4; ++j) {
        if (base + j < NINT) rp[base + j] = run;
        run += v[j];
    }
    if (tid == 255) bsum[rel * 512 + blockIdx.x] = ls[255];
}

// ---------------- CSR build: scan of block sums (single block per relation) ----------------
__global__ __launch_bounds__(512) void scan2_kernel(int* __restrict__ bsum)
{
    int* bs = bsum + blockIdx.y * 512;
    __shared__ int ls[512];
    const int tid = threadIdx.x;
    int v = (tid < NB_SCAN) ? bs[tid] : 0;
    ls[tid] = v;
    __syncthreads();
    for (int off = 1; off < 512; off <<= 1) {
        int t = (tid >= off) ? ls[tid - off] : 0;
        __syncthreads();
        ls[tid] += t;
        __syncthreads();
    }
    bs[tid] = ls[tid] - v;   // exclusive
}

// ---------------- CSR build: add block offsets ----------------
__global__ __launch_bounds__(256) void scan3_kernel(
    int* __restrict__ rp_si, int* __restrict__ rp_m, const int* __restrict__ bsum)
{
    int i = blockIdx.x * 256 + threadIdx.x;
    if (i >= NINT) return;
    int rel = blockIdx.y;
    int* rp = rel ? rp_m : rp_si;
    rp[i] += bsum[rel * 512 + (i >> 10)];
}

// ---------------- CSR build: bucket fill ----------------
__global__ __launch_bounds__(256) void fill_kernel(
    const int* __restrict__ src_si, const int* __restrict__ dst_si,
    const int* __restrict__ src_m,  const int* __restrict__ dst_m,
    const int* __restrict__ rp_si,  const int* __restrict__ rp_m,
    int* __restrict__ cur_si, int* __restrict__ cur_m,
    int* __restrict__ ei_si,  int* __restrict__ ei_m)
{
    int e = blockIdx.x * 256 + threadIdx.x;
    if (e >= NEDGE) return;
    if (blockIdx.y == 0) {
        int dn = dst_si[e], sn = src_si[e];
        int pos = atomicAdd(&cur_si[dn], 1);
        ei_si[rp_si[dn] + pos] = sn;
    } else {
        int dn = dst_m[e], sn = src_m[e];
        int pos = atomicAdd(&cur_m[dn], 1);
        ei_m[rp_m[dn] + pos] = sn;
    }
}

// ---------------- fused: x_int@Wi + gather-mean + layer2 + readout ----------------
// one 32-lane group per int node, 8 nodes per 256-thread block (NINT % 8 == 0)
__global__ __launch_bounds__(256) void final_kernel(
    const float* __restrict__ x_int,
    const float* __restrict__ Wit,   // [32][64] transposed
    const float* __restrict__ bi,    // [32]
    const float* __restrict__ p_si, const float* __restrict__ p_m,
    const float* __restrict__ s_si, const float* __restrict__ s_m,
    const int* __restrict__ rp_si, const int* __restrict__ deg_si, const int* __restrict__ ei_si,
    const int* __restrict__ rp_m,  const int* __restrict__ deg_m,  const int* __restrict__ ei_m,
    const float* __restrict__ v, const float* __restrict__ c0,
    float* __restrict__ out)
{
    __shared__ float xls[8 * 64];
    const int tid = threadIdx.x;
    const long node0 = (long)blockIdx.x * 8;
    const int f = tid & 31;
    const int grp = tid >> 5;
    const long node = node0 + grp;

    // stage 8 x_int rows (512 floats) into LDS, coalesced float2 per thread
    {
        int idx = tid * 2;
        *(float2*)&xls[idx] = *(const float2*)&x_int[node0 * 64 + idx];
    }
    // Wi column f into registers (8 KB array, L2-resident)
    float wcol[64];
    #pragma unroll
    for (int k4 = 0; k4 < 16; ++k4) {
        float4 t = *(const float4*)&Wit[f * 64 + k4 * 4];
        wcol[k4 * 4 + 0] = t.x; wcol[k4 * 4 + 1] = t.y;
        wcol[k4 * 4 + 2] = t.z; wcol[k4 * 4 + 3] = t.w;
    }
    __syncthreads();

    // r = bi[f] + x_int[node] . Wi[:,f]   (LDS broadcast reads, 2-way max = free)
    float r = bi[f];
    const float* xrow = &xls[grp * 64];
    #pragma unroll
    for (int k4 = 0; k4 < 16; ++k4) {
        float4 xv = *(const float4*)&xrow[k4 * 4];
        r = fmaf(xv.x, wcol[k4 * 4 + 0], r);
        r = fmaf(xv.y, wcol[k4 * 4 + 1], r);
        r = fmaf(xv.z, wcol[k4 * 4 + 2], r);
        r = fmaf(xv.w, wcol[k4 * 4 + 3], r);
    }

    // gather-mean over si edges
    int ds = deg_si[node], rs = rp_si[node];
    float a_si = 0.f, ss_si = 0.f;
    for (int e = 0; e < ds; ++e) {
        int sn = ei_si[rs + e];                 // broadcast load
        a_si  += p_si[(long)sn * 32 + f];       // coalesced 128B row gather (L2-resident)
        ss_si += s_si[sn];
    }
    int dm = deg_m[node], rm = rp_m[node];
    float a_m = 0.f, ss_m = 0.f;
    for (int e = 0; e < dm; ++e) {
        int sn = ei_m[rm + e];
        a_m  += p_m[(long)sn * 32 + f];
        ss_m += s_m[sn];
    }
    float csi = fmaxf((float)ds, 1.0f);
    float cm  = fmaxf((float)dm, 1.0f);

    float h = fmaxf(r + 0.5f * (a_si / csi + a_m / cm), 0.0f);
    float t = h * v[f];
    #pragma unroll
    for (int off = 16; off > 0; off >>= 1) t += __shfl_xor(t, off);
    if (f == 0)
        out[node] = t + 0.5f * (ss_si / csi + ss_m / cm) + c0[0];
}

extern "C" void kernel_launch(void* const* d_in, const int* in_sizes, int n_in,
                              void* d_out, int out_size, void* d_ws, size_t ws_size,
                              hipStream_t stream)
{
    const float* x_si     = (const float*)d_in[0];
    const float* x_m      = (const float*)d_in[1];
    const float* x_int    = (const float*)d_in[2];
    const float* W1l_si2i = (const float*)d_in[3];
    const float* W1r_si2i = (const float*)d_in[4];
    const float* b1_si2i  = (const float*)d_in[5];
    const float* W1l_m2i  = (const float*)d_in[6];
    const float* W1r_m2i  = (const float*)d_in[7];
    const float* b1_m2i   = (const float*)d_in[8];
    const float* W1l_si   = (const float*)d_in[9];
    const float* W1r_si   = (const float*)d_in[10];
    const float* b1_si    = (const float*)d_in[11];
    const float* W1l_m    = (const float*)d_in[12];
    const float* W1r_m    = (const float*)d_in[13];
    const float* b1_m     = (const float*)d_in[14];
    const float* W2l_si2i = (const float*)d_in[15];
    const float* W2r_si2i = (const float*)d_in[16];
    const float* b2_si2i  = (const float*)d_in[17];
    const float* W2l_m2i  = (const float*)d_in[18];
    const float* W2r_m2i  = (const float*)d_in[19];
    const float* b2_m2i   = (const float*)d_in[20];
    // d_in[21..26] unused (don't reach the readout)
    const float* Wlin     = (const float*)d_in[27];
    const float* blin     = (const float*)d_in[28];
    const int* src_si2i   = (const int*)d_in[29];
    const int* dst_si2i   = (const int*)d_in[30];
    const int* src_m2i    = (const int*)d_in[31];
    const int* dst_m2i    = (const int*)d_in[32];

    float* ws = (float*)d_ws;
    if (ws_size < (size_t)OFF_END * sizeof(float)) return;

    int* deg_si = (int*)(ws + OFF_DEG);
    int* deg_m  = deg_si + 500000;
    int* cur_si = deg_si + 1000000;
    int* cur_m  = deg_si + 1500000;
    int* rp_si  = (int*)(ws + OFF_RP);
    int* rp_m   = rp_si + 500000;
    int* ei_si  = (int*)(ws + OFF_EI);
    int* ei_m   = ei_si + 500000;
    int* bsum   = (int*)(ws + OFF_BS);

    prep_kernel<<<1, 256, 0, stream>>>(
        W1l_si2i, W1l_si, W1r_si, W1l_m2i, W1l_m, W1r_m,
        W1r_si2i, W1r_m2i, b1_si2i, b1_m2i,
        W2l_si2i, W2l_m2i, W2r_si2i, W2r_m2i,
        b2_si2i, b2_m2i, Wlin, blin,
        ws + OFF_WSI, ws + OFF_WM, ws + OFF_WIT, ws + OFF_BI,
        ws + OFF_USI, ws + OFF_UM, ws + OFF_V, ws + OFF_C0);

    // zero deg + cursor (8 MB) — the only zeroing needed now
    hipMemsetAsync(deg_si, 0, 2000000 * sizeof(int), stream);

    // CSR build for both relations
    dim3 egrid((NEDGE + 255) / 256, 2);
    hist_kernel<<<egrid, 256, 0, stream>>>(dst_si2i, dst_m2i, deg_si, deg_m);
    scan1_kernel<<<dim3(NB_SCAN, 2), 256, 0, stream>>>(deg_si, deg_m, rp_si, rp_m, bsum);
    scan2_kernel<<<dim3(1, 2), 512, 0, stream>>>(bsum);
    scan3_kernel<<<dim3((NINT + 255) / 256, 2), 256, 0, stream>>>(rp_si, rp_m, bsum);
    fill_kernel<<<egrid, 256, 0, stream>>>(src_si2i, dst_si2i, src_m2i, dst_m2i,
                                           rp_si, rp_m, cur_si, cur_m, ei_si, ei_m);

    // layer-1 projections for src node types
    gemm_src<<<(NSI + 63) / 64, 256, 0, stream>>>(x_si, ws + OFF_WSI, b1_si, ws + OFF_PSI, ws + OFF_HSI, NSI);
    gemm_src<<<(NM  + 63) / 64, 256, 0, stream>>>(x_m,  ws + OFF_WM,  b1_m,  ws + OFF_PM,  ws + OFF_HM,  NM);

    s_kernel<<<(NSI + NM) / 8, 256, 0, stream>>>(ws + OFF_HSI, ws + OFF_HM,
                                                 ws + OFF_USI, ws + OFF_UM,
                                                 ws + OFF_SSI, ws + OFF_SM);

    // fused int-node projection + gather-mean + layer2 + readout
    final_kernel<<<NINT / 8, 256, 0, stream>>>(x_int, ws + OFF_WIT, ws + OFF_BI,
                                               ws + OFF_PSI, ws + OFF_PM,
                                               ws + OFF_SSI, ws + OFF_SM,
                                               rp_si, deg_si, ei_si,
                                               rp_m,  deg_m,  ei_m,
                                               ws + OFF_V, ws + OFF_C0, (float*)d_out);
}

// Round 3
// 661.425 us; speedup vs baseline: 1.8373x; 1.8373x over previous
//
#include <hip/hip_runtime.h>
#include <cstdint>

#define NSI   100000
#define NM    100000
#define NINT  500000
#define NEDGE 500000
#define NB_SCAN 489   // ceil(NINT/1024)

// ---------------- workspace layout (float offsets) ----------------
static const long OFF_WSI  = 0;                       // [128][64] cat: cols 0-31 W1l_si2i, 32-63 W1l_si+W1r_si
static const long OFF_WM   = 8192;                    // [128][64] same for m
static const long OFF_WI   = 16384;                   // [64][32] 0.5*(W1r_si2i+W1r_m2i)
static const long OFF_USI  = 18432;                   // [32] W2l_si2i @ wlin
static const long OFF_UM   = 18464;                   // [32]
static const long OFF_V    = 18496;                   // [32] 0.5*(W2r_si2i+W2r_m2i) @ wlin
static const long OFF_C0   = 18528;                   // [1] scalar bias (pad 32)
static const long OFF_BI   = 18560;                   // [32] 0.5*(b1_si2i+b1_m2i)
static const long OFF_PSI  = 18592;                   // [NSI][32] x_si @ W1l_si2i   (128B-aligned: 18592*4 % 128 == 0)
static const long OFF_HSI  = OFF_PSI + 3200000;       // [NSI][32] relu(x_si@(W1l+W1r)+b)
static const long OFF_PM   = OFF_HSI + 3200000;
static const long OFF_HM   = OFF_PM + 3200000;
static const long OFF_SSI  = OFF_HM + 3200000;        // [NSI] layer2 scalar per src node
static const long OFF_SM   = OFF_SSI + 100000;
static const long OFF_RI   = OFF_SM + 100000;         // [NINT][32] x_int@Wi + bi
// int region (cast to int*)
static const long OFF_DEG  = OFF_RI + 16000000;       // deg_si, deg_m, cur_si, cur_m (4x500K, ZEROED)
static const long OFF_RP   = OFF_DEG + 2000000;       // rp_si, rp_m
static const long OFF_EI   = OFF_RP + 1000000;        // ei_si, ei_m (src indices bucketed by dst)
static const long OFF_BS   = OFF_EI + 1000000;        // block sums 2x512
static const long OFF_END  = OFF_BS + 1024;           // ~33M floats = 132 MB

// ---------------- prep: combined weight tensors ----------------
__global__ __launch_bounds__(256) void prep_kernel(
    const float* __restrict__ W1l_si2i, const float* __restrict__ W1l_si, const float* __restrict__ W1r_si,
    const float* __restrict__ W1l_m2i,  const float* __restrict__ W1l_m,  const float* __restrict__ W1r_m,
    const float* __restrict__ W1r_si2i, const float* __restrict__ W1r_m2i,
    const float* __restrict__ b1_si2i,  const float* __restrict__ b1_m2i,
    const float* __restrict__ W2l_si2i, const float* __restrict__ W2l_m2i,
    const float* __restrict__ W2r_si2i, const float* __restrict__ W2r_m2i,
    const float* __restrict__ b2_si2i,  const float* __restrict__ b2_m2i,
    const float* __restrict__ Wlin,     const float* __restrict__ blin,
    float* __restrict__ Wsi, float* __restrict__ Wm, float* __restrict__ Wi, float* __restrict__ bi,
    float* __restrict__ u_si, float* __restrict__ u_m, float* __restrict__ v, float* __restrict__ c0)
{
    const int tid = threadIdx.x;
    for (int idx = tid; idx < 128 * 64; idx += 256) {
        int k = idx >> 6, c = idx & 63;
        float a, b;
        if (c < 32) { a = W1l_si2i[k * 32 + c];      b = W1l_m2i[k * 32 + c]; }
        else { int cc = c - 32;
               a = W1l_si[k * 32 + cc] + W1r_si[k * 32 + cc];
               b = W1l_m[k * 32 + cc]  + W1r_m[k * 32 + cc]; }
        Wsi[idx] = a; Wm[idx] = b;
    }
    for (int idx = tid; idx < 64 * 32; idx += 256)
        Wi[idx] = 0.5f * (W1r_si2i[idx] + W1r_m2i[idx]);
    if (tid < 32) {
        bi[tid] = 0.5f * (b1_si2i[tid] + b1_m2i[tid]);
        float us = 0.f, um = 0.f, vv = 0.f;
        for (int k = 0; k < 16; ++k) {
            float wl = Wlin[k];
            us += W2l_si2i[tid * 16 + k] * wl;
            um += W2l_m2i[tid * 16 + k] * wl;
            vv += 0.5f * (W2r_si2i[tid * 16 + k] + W2r_m2i[tid * 16 + k]) * wl;
        }
        u_si[tid] = us; u_m[tid] = um; v[tid] = vv;
    }
    if (tid == 0) {
        float c = blin[0];
        for (int k = 0; k < 16; ++k) c += 0.5f * (b2_si2i[k] + b2_m2i[k]) * Wlin[k];
        c0[0] = c;
    }
}

// ---------------- GEMM for src node types: K=128, M=64 (P|H), 64-row tile ----------------
__global__ __launch_bounds__(256) void gemm_src(
    const float* __restrict__ X, const float* __restrict__ Wcat, const float* __restrict__ bias,
    float* __restrict__ P, float* __restrict__ H, int N)
{
    __shared__ float xs[64 * 132];
    __shared__ float lw[64 * 64];
    const int tid = threadIdx.x;
    const long row_base = (long)blockIdx.x * 64;

    #pragma unroll
    for (int i = 0; i < 8; ++i) {
        int idx = tid + i * 256;
        int r = idx >> 5, k4 = idx & 31;
        long rr = row_base + r;
        float4 val = make_float4(0.f, 0.f, 0.f, 0.f);
        if (rr < N) val = ((const float4*)X)[rr * 32 + k4];
        *(float4*)&xs[r * 132 + k4 * 4] = val;
    }

    const int r0 = tid & 15;
    const int c0 = (tid >> 4) * 4;
    float acc[4][4] = {{0.f}};

    for (int half = 0; half < 2; ++half) {
        __syncthreads();
        #pragma unroll
        for (int i = 0; i < 4; ++i) {
            int idx = tid + i * 256;
            ((float4*)lw)[idx] = ((const float4*)Wcat)[half * 1024 + idx];
        }
        __syncthreads();
        const float* xb = xs + half * 64;
        #pragma unroll 4
        for (int k = 0; k < 64; k += 4) {
            float4 xr[4];
            #pragma unroll
            for (int j = 0; j < 4; ++j)
                xr[j] = *(const float4*)&xb[(r0 + 16 * j) * 132 + k];
            #pragma unroll
            for (int kk = 0; kk < 4; ++kk) {
                float4 wv = *(const float4*)&lw[(k + kk) * 64 + c0];
                #pragma unroll
                for (int j = 0; j < 4; ++j) {
                    float xv = (kk == 0) ? xr[j].x : (kk == 1) ? xr[j].y : (kk == 2) ? xr[j].z : xr[j].w;
                    acc[j][0] = fmaf(xv, wv.x, acc[j][0]);
                    acc[j][1] = fmaf(xv, wv.y, acc[j][1]);
                    acc[j][2] = fmaf(xv, wv.z, acc[j][2]);
                    acc[j][3] = fmaf(xv, wv.w, acc[j][3]);
                }
            }
        }
    }

    #pragma unroll
    for (int j = 0; j < 4; ++j) {
        long rr = row_base + r0 + 16 * j;
        if (rr >= N) continue;
        if (c0 < 32) {
            *(float4*)&P[rr * 32 + c0] = make_float4(acc[j][0], acc[j][1], acc[j][2], acc[j][3]);
        } else {
            const int cc = c0 - 32;
            float4 o;
            o.x = fmaxf(acc[j][0] + bias[cc + 0], 0.f);
            o.y = fmaxf(acc[j][1] + bias[cc + 1], 0.f);
            o.z = fmaxf(acc[j][2] + bias[cc + 2], 0.f);
            o.w = fmaxf(acc[j][3] + bias[cc + 3], 0.f);
            *(float4*)&H[rr * 32 + cc] = o;
        }
    }
}

// ---------------- GEMM for int nodes: K=64, M=32, 64-row tile, 128 threads ----------------
__global__ __launch_bounds__(128) void gemm_int(
    const float* __restrict__ X, const float* __restrict__ W,
    const float* __restrict__ bi,
    float* __restrict__ R, int N)
{
    __shared__ float xs[64 * 68];
    __shared__ float lw[64 * 32];
    const int tid = threadIdx.x;
    const long row_base = (long)blockIdx.x * 64;

    #pragma unroll
    for (int i = 0; i < 4; ++i)
        ((float4*)lw)[tid + i * 128] = ((const float4*)W)[tid + i * 128];
    #pragma unroll
    for (int i = 0; i < 8; ++i) {
        int idx = tid + i * 128;
        int r = idx >> 4, k4 = idx & 15;
        long rr = row_base + r;
        float4 val = make_float4(0.f, 0.f, 0.f, 0.f);
        if (rr < N) val = ((const float4*)X)[rr * 16 + k4];
        *(float4*)&xs[r * 68 + k4 * 4] = val;
    }
    __syncthreads();

    const int r0 = tid & 15;
    const int c0 = (tid >> 4) * 4;   // 0..28
    float acc[4][4] = {{0.f}};
    #pragma unroll 4
    for (int k = 0; k < 64; k += 4) {
        float4 xr[4];
        #pragma unroll
        for (int j = 0; j < 4; ++j)
            xr[j] = *(const float4*)&xs[(r0 + 16 * j) * 68 + k];
        #pragma unroll
        for (int kk = 0; kk < 4; ++kk) {
            float4 wv = *(const float4*)&lw[(k + kk) * 32 + c0];
            #pragma unroll
            for (int j = 0; j < 4; ++j) {
                float xv = (kk == 0) ? xr[j].x : (kk == 1) ? xr[j].y : (kk == 2) ? xr[j].z : xr[j].w;
                acc[j][0] = fmaf(xv, wv.x, acc[j][0]);
                acc[j][1] = fmaf(xv, wv.y, acc[j][1]);
                acc[j][2] = fmaf(xv, wv.z, acc[j][2]);
                acc[j][3] = fmaf(xv, wv.w, acc[j][3]);
            }
        }
    }
    #pragma unroll
    for (int j = 0; j < 4; ++j) {
        long rr = row_base + r0 + 16 * j;
        if (rr >= N) continue;
        float4 o;
        o.x = acc[j][0] + bi[c0 + 0];
        o.y = acc[j][1] + bi[c0 + 1];
        o.z = acc[j][2] + bi[c0 + 2];
        o.w = acc[j][3] + bi[c0 + 3];
        *(float4*)&R[rr * 32 + c0] = o;
    }
}

// ---------------- per-src-node layer-2 scalar: s[n] = h[n] . u ----------------
__global__ __launch_bounds__(256) void s_kernel(
    const float* __restrict__ h_si, const float* __restrict__ h_m,
    const float* __restrict__ u_si, const float* __restrict__ u_m,
    float* __restrict__ s_si, float* __restrict__ s_m)
{
    long gid = (long)blockIdx.x * 256 + threadIdx.x;
    long node = gid >> 5;
    int f = (int)(gid & 31);
    if (node >= (long)(NSI + NM)) return;
    const float* h; const float* u; float* s; long n;
    if (node < NSI) { h = h_si; u = u_si; s = s_si; n = node; }
    else            { h = h_m;  u = u_m;  s = s_m;  n = node - NSI; }
    float t = h[n * 32 + f] * u[f];
    #pragma unroll
    for (int off = 16; off > 0; off >>= 1) t += __shfl_xor(t, off);
    if (f == 0) s[n] = t;
}

// ---------------- CSR build: histogram ----------------
__global__ __launch_bounds__(256) void hist_kernel(
    const int* __restrict__ dst_si, const int* __restrict__ dst_m,
    int* __restrict__ deg_si, int* __restrict__ deg_m)
{
    int e = blockIdx.x * 256 + threadIdx.x;
    if (e >= NEDGE) return;
    if (blockIdx.y == 0) atomicAdd(&deg_si[dst_si[e]], 1);
    else                 atomicAdd(&deg_m[dst_m[e]], 1);
}

// ---------------- CSR build: block-level exclusive scan (1024 elems/block) ----------------
__global__ __launch_bounds__(256) void scan1_kernel(
    const int* __restrict__ deg_si, const int* __restrict__ deg_m,
    int* __restrict__ rp_si, int* __restrict__ rp_m, int* __restrict__ bsum)
{
    const int rel = blockIdx.y;
    const int* deg = rel ? deg_m : deg_si;
    int* rp = rel ? rp_m : rp_si;
    __shared__ int ls[256];
    const int tid = threadIdx.x;
    const int base = blockIdx.x * 1024 + tid * 4;
    int v[4];
    #pragma unroll
    for (int j = 0; j < 4; ++j) v[j] = (base + j < NINT) ? deg[base + j] : 0;
    int tsum = v[0] + v[1] + v[2] + v[3];
    ls[tid] = tsum;
    __syncthreads();
    for (int off = 1; off < 256; off <<= 1) {
        int t = (tid >= off) ? ls[tid - off] : 0;
        __syncthreads();
        ls[tid] += t;
        __syncthreads();
    }
    int run = ls[tid] - tsum;
    #pragma unroll
    for (int j = 0; j < 4; ++j) {
        if (base + j < NINT) rp[base + j] = run;
        run += v[j];
    }
    if (tid == 255) bsum[rel * 512 + blockIdx.x] = ls[255];
}

// ---------------- CSR build: scan of block sums (single block per relation) ----------------
__global__ __launch_bounds__(512) void scan2_kernel(int* __restrict__ bsum)
{
    int* bs = bsum + blockIdx.y * 512;
    __shared__ int ls[512];
    const int tid = threadIdx.x;
    int v = (tid < NB_SCAN) ? bs[tid] : 0;
    ls[tid] = v;
    __syncthreads();
    for (int off = 1; off < 512; off <<= 1) {
        int t = (tid >= off) ? ls[tid - off] : 0;
        __syncthreads();
        ls[tid] += t;
        __syncthreads();
    }
    bs[tid] = ls[tid] - v;   // exclusive
}

// ---------------- CSR build: add block offsets ----------------
__global__ __launch_bounds__(256) void scan3_kernel(
    int* __restrict__ rp_si, int* __restrict__ rp_m, const int* __restrict__ bsum)
{
    int i = blockIdx.x * 256 + threadIdx.x;
    if (i >= NINT) return;
    int rel = blockIdx.y;
    int* rp = rel ? rp_m : rp_si;
    rp[i] += bsum[rel * 512 + (i >> 10)];
}

// ---------------- CSR build: bucket fill ----------------
__global__ __launch_bounds__(256) void fill_kernel(
    const int* __restrict__ src_si, const int* __restrict__ dst_si,
    const int* __restrict__ src_m,  const int* __restrict__ dst_m,
    const int* __restrict__ rp_si,  const int* __restrict__ rp_m,
    int* __restrict__ cur_si, int* __restrict__ cur_m,
    int* __restrict__ ei_si,  int* __restrict__ ei_m)
{
    int e = blockIdx.x * 256 + threadIdx.x;
    if (e >= NEDGE) return;
    if (blockIdx.y == 0) {
        int dn = dst_si[e], sn = src_si[e];
        int pos = atomicAdd(&cur_si[dn], 1);
        ei_si[rp_si[dn] + pos] = sn;
    } else {
        int dn = dst_m[e], sn = src_m[e];
        int pos = atomicAdd(&cur_m[dn], 1);
        ei_m[rp_m[dn] + pos] = sn;
    }
}

// ---------------- lean gather epilogue: mean-gather + layer2 + readout ----------------
// one 32-lane group per int node; no LDS; parallel dependency chains for both relations
__global__ __launch_bounds__(256) void final_gather(
    const float* __restrict__ r_int,
    const float* __restrict__ p_si, const float* __restrict__ p_m,
    const float* __restrict__ s_si, const float* __restrict__ s_m,
    const int* __restrict__ rp_si, const int* __restrict__ deg_si, const int* __restrict__ ei_si,
    const int* __restrict__ rp_m,  const int* __restrict__ deg_m,  const int* __restrict__ ei_m,
    const float* __restrict__ v, const float* __restrict__ c0,
    float* __restrict__ out)
{
    long gid = (long)blockIdx.x * 256 + threadIdx.x;
    long node = gid >> 5;
    int f = (int)(gid & 31);
    if (node >= NINT) return;

    // level 0: all independent — issued together
    int ds = deg_si[node];
    int dm = deg_m[node];
    int rs = rp_si[node];
    int rm = rp_m[node];
    float r  = r_int[node * 32 + f];   // coalesced, independent of the chain
    float vf = v[f];

    // level 1: first-edge indices, predicated with safe index 0
    int sn_s = (ds > 0) ? ei_si[rs] : 0;
    int sn_m = (dm > 0) ? ei_m[rm] : 0;

    // level 2: both relations' gathers in flight simultaneously
    float ps = p_si[(long)sn_s * 32 + f];
    float pm = p_m[(long)sn_m * 32 + f];
    float qs = s_si[sn_s];
    float qm = s_m[sn_m];

    float a_si = (ds > 0) ? ps : 0.f;
    float a_m  = (dm > 0) ? pm : 0.f;
    float ss_si = (ds > 0) ? qs : 0.f;
    float ss_m  = (dm > 0) ? qm : 0.f;

    // rare tail: deg >= 2 (P ~ 0.26 for Poisson(1))
    for (int e = 1; e < ds; ++e) {
        int sn = ei_si[rs + e];
        a_si  += p_si[(long)sn * 32 + f];
        ss_si += s_si[sn];
    }
    for (int e = 1; e < dm; ++e) {
        int sn = ei_m[rm + e];
        a_m  += p_m[(long)sn * 32 + f];
        ss_m += s_m[sn];
    }

    float csi = fmaxf((float)ds, 1.0f);
    float cm  = fmaxf((float)dm, 1.0f);

    float h = fmaxf(r + 0.5f * (a_si / csi + a_m / cm), 0.0f);
    float t = h * vf;
    #pragma unroll
    for (int off = 16; off > 0; off >>= 1) t += __shfl_xor(t, off);
    if (f == 0)
        out[node] = t + 0.5f * (ss_si / csi + ss_m / cm) + c0[0];
}

extern "C" void kernel_launch(void* const* d_in, const int* in_sizes, int n_in,
                              void* d_out, int out_size, void* d_ws, size_t ws_size,
                              hipStream_t stream)
{
    const float* x_si     = (const float*)d_in[0];
    const float* x_m      = (const float*)d_in[1];
    const float* x_int    = (const float*)d_in[2];
    const float* W1l_si2i = (const float*)d_in[3];
    const float* W1r_si2i = (const float*)d_in[4];
    const float* b1_si2i  = (const float*)d_in[5];
    const float* W1l_m2i  = (const float*)d_in[6];
    const float* W1r_m2i  = (const float*)d_in[7];
    const float* b1_m2i   = (const float*)d_in[8];
    const float* W1l_si   = (const float*)d_in[9];
    const float* W1r_si   = (const float*)d_in[10];
    const float* b1_si    = (const float*)d_in[11];
    const float* W1l_m    = (const float*)d_in[12];
    const float* W1r_m    = (const float*)d_in[13];
    const float* b1_m     = (const float*)d_in[14];
    const float* W2l_si2i = (const float*)d_in[15];
    const float* W2r_si2i = (const float*)d_in[16];
    const float* b2_si2i  = (const float*)d_in[17];
    const float* W2l_m2i  = (const float*)d_in[18];
    const float* W2r_m2i  = (const float*)d_in[19];
    const float* b2_m2i   = (const float*)d_in[20];
    // d_in[21..26] unused (don't reach the readout)
    const float* Wlin     = (const float*)d_in[27];
    const float* blin     = (const float*)d_in[28];
    const int* src_si2i   = (const int*)d_in[29];
    const int* dst_si2i   = (const int*)d_in[30];
    const int* src_m2i    = (const int*)d_in[31];
    const int* dst_m2i    = (const int*)d_in[32];

    float* ws = (float*)d_ws;
    if (ws_size < (size_t)OFF_END * sizeof(float)) return;

    int* deg_si = (int*)(ws + OFF_DEG);
    int* deg_m  = deg_si + 500000;
    int* cur_si = deg_si + 1000000;
    int* cur_m  = deg_si + 1500000;
    int* rp_si  = (int*)(ws + OFF_RP);
    int* rp_m   = rp_si + 500000;
    int* ei_si  = (int*)(ws + OFF_EI);
    int* ei_m   = ei_si + 500000;
    int* bsum   = (int*)(ws + OFF_BS);

    prep_kernel<<<1, 256, 0, stream>>>(
        W1l_si2i, W1l_si, W1r_si, W1l_m2i, W1l_m, W1r_m,
        W1r_si2i, W1r_m2i, b1_si2i, b1_m2i,
        W2l_si2i, W2l_m2i, W2r_si2i, W2r_m2i,
        b2_si2i, b2_m2i, Wlin, blin,
        ws + OFF_WSI, ws + OFF_WM, ws + OFF_WI, ws + OFF_BI,
        ws + OFF_USI, ws + OFF_UM, ws + OFF_V, ws + OFF_C0);

    // zero deg + cursor (8 MB)
    hipMemsetAsync(deg_si, 0, 2000000 * sizeof(int), stream);

    // CSR build for both relations
    dim3 egrid((NEDGE + 255) / 256, 2);
    hist_kernel<<<egrid, 256, 0, stream>>>(dst_si2i, dst_m2i, deg_si, deg_m);
    scan1_kernel<<<dim3(NB_SCAN, 2), 256, 0, stream>>>(deg_si, deg_m, rp_si, rp_m, bsum);
    scan2_kernel<<<dim3(1, 2), 512, 0, stream>>>(bsum);
    scan3_kernel<<<dim3((NINT + 255) / 256, 2), 256, 0, stream>>>(rp_si, rp_m, bsum);
    fill_kernel<<<egrid, 256, 0, stream>>>(src_si2i, dst_si2i, src_m2i, dst_m2i,
                                           rp_si, rp_m, cur_si, cur_m, ei_si, ei_m);

    // layer-1 projections
    gemm_src<<<(NSI + 63) / 64, 256, 0, stream>>>(x_si, ws + OFF_WSI, b1_si, ws + OFF_PSI, ws + OFF_HSI, NSI);
    gemm_src<<<(NM  + 63) / 64, 256, 0, stream>>>(x_m,  ws + OFF_WM,  b1_m,  ws + OFF_PM,  ws + OFF_HM,  NM);
    gemm_int<<<(NINT + 63) / 64, 128, 0, stream>>>(x_int, ws + OFF_WI, ws + OFF_BI, ws + OFF_RI, NINT);

    s_kernel<<<(NSI + NM) / 8, 256, 0, stream>>>(ws + OFF_HSI, ws + OFF_HM,
                                                 ws + OFF_USI, ws + OFF_UM,
                                                 ws + OFF_SSI, ws + OFF_SM);

    // gather-mean + layer2 + readout
    final_gather<<<NINT / 8, 256, 0, stream>>>(ws + OFF_RI,
                                               ws + OFF_PSI, ws + OFF_PM,
                                               ws + OFF_SSI, ws + OFF_SM,
                                               rp_si, deg_si, ei_si,
                                               rp_m,  deg_m,  ei_m,
                                               ws + OFF_V, ws + OFF_C0, (float*)d_out);
}

// Round 4
// 593.246 us; speedup vs baseline: 2.0484x; 1.1149x over previous
//
#include <hip/hip_runtime.h>
#include <cstdint>

#define NSI   100000
#define NM    100000
#define NINT  500000
#define NEDGE 500000
#define NB_SCAN 489   // ceil(NINT/1024)

// ---------------- workspace layout (float offsets) ----------------
static const long OFF_WSI  = 0;                       // [128][64] cat: cols 0-31 W1l_si2i, 32-63 W1l_si+W1r_si
static const long OFF_WM   = 8192;                    // [128][64] same for m
static const long OFF_WI   = 16384;                   // [64][32] 0.5*(W1r_si2i+W1r_m2i)
static const long OFF_USI  = 18432;                   // [32] W2l_si2i @ wlin
static const long OFF_UM   = 18464;                   // [32]
static const long OFF_V    = 18496;                   // [32] 0.5*(W2r_si2i+W2r_m2i) @ wlin
static const long OFF_C0   = 18528;                   // [1] scalar bias (pad 32)
static const long OFF_BI   = 18560;                   // [32] 0.5*(b1_si2i+b1_m2i)
static const long OFF_PSI  = 18592;                   // [NSI][32] x_si @ W1l_si2i (16B aligned)
static const long OFF_PM   = OFF_PSI + 3200000;
static const long OFF_SSI  = OFF_PM + 3200000;        // [NSI] layer2 scalar per src node
static const long OFF_SM   = OFF_SSI + 100000;
static const long OFF_RI   = OFF_SM + 100000;         // [NINT][32] x_int@Wi + bi
// int region (cast to int*)
static const long OFF_DEG  = OFF_RI + 16000000;       // deg_si, deg_m (2x500K, ZEROED; consumed by fill)
static const long OFF_RP   = OFF_DEG + 1000000;       // rp_si[500001] @ +0, rp_m[500001] @ +500032
static const long OFF_EI   = OFF_RP + 1000064;        // ei_si, ei_m
static const long OFF_BS   = OFF_EI + 1000000;        // block sums 2x512
static const long OFF_END  = OFF_BS + 1024;           // ~25.6M floats = 102 MB

// ---------------- prep: combined weight tensors ----------------
__global__ __launch_bounds__(256) void prep_kernel(
    const float* __restrict__ W1l_si2i, const float* __restrict__ W1l_si, const float* __restrict__ W1r_si,
    const float* __restrict__ W1l_m2i,  const float* __restrict__ W1l_m,  const float* __restrict__ W1r_m,
    const float* __restrict__ W1r_si2i, const float* __restrict__ W1r_m2i,
    const float* __restrict__ b1_si2i,  const float* __restrict__ b1_m2i,
    const float* __restrict__ W2l_si2i, const float* __restrict__ W2l_m2i,
    const float* __restrict__ W2r_si2i, const float* __restrict__ W2r_m2i,
    const float* __restrict__ b2_si2i,  const float* __restrict__ b2_m2i,
    const float* __restrict__ Wlin,     const float* __restrict__ blin,
    float* __restrict__ Wsi, float* __restrict__ Wm, float* __restrict__ Wi, float* __restrict__ bi,
    float* __restrict__ u_si, float* __restrict__ u_m, float* __restrict__ v, float* __restrict__ c0,
    int* __restrict__ rp_si, int* __restrict__ rp_m)
{
    const int tid = threadIdx.x;
    for (int idx = tid; idx < 128 * 64; idx += 256) {
        int k = idx >> 6, c = idx & 63;
        float a, b;
        if (c < 32) { a = W1l_si2i[k * 32 + c];      b = W1l_m2i[k * 32 + c]; }
        else { int cc = c - 32;
               a = W1l_si[k * 32 + cc] + W1r_si[k * 32 + cc];
               b = W1l_m[k * 32 + cc]  + W1r_m[k * 32 + cc]; }
        Wsi[idx] = a; Wm[idx] = b;
    }
    for (int idx = tid; idx < 64 * 32; idx += 256)
        Wi[idx] = 0.5f * (W1r_si2i[idx] + W1r_m2i[idx]);
    if (tid < 32) {
        bi[tid] = 0.5f * (b1_si2i[tid] + b1_m2i[tid]);
        float us = 0.f, um = 0.f, vv = 0.f;
        for (int k = 0; k < 16; ++k) {
            float wl = Wlin[k];
            us += W2l_si2i[tid * 16 + k] * wl;
            um += W2l_m2i[tid * 16 + k] * wl;
            vv += 0.5f * (W2r_si2i[tid * 16 + k] + W2r_m2i[tid * 16 + k]) * wl;
        }
        u_si[tid] = us; u_m[tid] = um; v[tid] = vv;
    }
    if (tid == 0) {
        float c = blin[0];
        for (int k = 0; k < 16; ++k) c += 0.5f * (b2_si2i[k] + b2_m2i[k]) * Wlin[k];
        c0[0] = c;
        rp_si[NINT] = NEDGE;   // CSR sentinels (deg[i] = rp[i+1]-rp[i])
        rp_m[NINT]  = NEDGE;
    }
}

// ---------------- GEMM for src node types: K=128, 64-row tile ----------------
// outputs: P[N][32] = X@W1l (cols 0-31) and s[N] = relu(X@(W1l+W1r)+b) . u (cols 32-63, reduced)
__global__ __launch_bounds__(256) void gemm_src(
    const float* __restrict__ X, const float* __restrict__ Wcat, const float* __restrict__ bias,
    const float* __restrict__ u,
    float* __restrict__ P, float* __restrict__ s_out, int N)
{
    __shared__ float xs[64 * 132];
    __shared__ float lw[64 * 64];
    __shared__ float sp[64 * 9];
    const int tid = threadIdx.x;
    const long row_base = (long)blockIdx.x * 64;

    #pragma unroll
    for (int i = 0; i < 8; ++i) {
        int idx = tid + i * 256;
        int r = idx >> 5, k4 = idx & 31;
        long rr = row_base + r;
        float4 val = make_float4(0.f, 0.f, 0.f, 0.f);
        if (rr < N) val = ((const float4*)X)[rr * 32 + k4];
        *(float4*)&xs[r * 132 + k4 * 4] = val;
    }

    const int r0 = tid & 15;
    const int c0 = (tid >> 4) * 4;
    float acc[4][4] = {{0.f}};

    for (int half = 0; half < 2; ++half) {
        __syncthreads();
        #pragma unroll
        for (int i = 0; i < 4; ++i) {
            int idx = tid + i * 256;
            ((float4*)lw)[idx] = ((const float4*)Wcat)[half * 1024 + idx];
        }
        __syncthreads();
        const float* xb = xs + half * 64;
        #pragma unroll 4
        for (int k = 0; k < 64; k += 4) {
            float4 xr[4];
            #pragma unroll
            for (int j = 0; j < 4; ++j)
                xr[j] = *(const float4*)&xb[(r0 + 16 * j) * 132 + k];
            #pragma unroll
            for (int kk = 0; kk < 4; ++kk) {
                float4 wv = *(const float4*)&lw[(k + kk) * 64 + c0];
                #pragma unroll
                for (int j = 0; j < 4; ++j) {
                    float xv = (kk == 0) ? xr[j].x : (kk == 1) ? xr[j].y : (kk == 2) ? xr[j].z : xr[j].w;
                    acc[j][0] = fmaf(xv, wv.x, acc[j][0]);
                    acc[j][1] = fmaf(xv, wv.y, acc[j][1]);
                    acc[j][2] = fmaf(xv, wv.z, acc[j][2]);
                    acc[j][3] = fmaf(xv, wv.w, acc[j][3]);
                }
            }
        }
    }

    // epilogue: P store (cols 0-31) or partial h.u into LDS (cols 32-63)
    #pragma unroll
    for (int j = 0; j < 4; ++j) {
        long rr = row_base + r0 + 16 * j;
        if (c0 < 32) {
            if (rr < N)
                *(float4*)&P[rr * 32 + c0] = make_float4(acc[j][0], acc[j][1], acc[j][2], acc[j][3]);
        } else {
            const int cc = c0 - 32;
            float h0 = fmaxf(acc[j][0] + bias[cc + 0], 0.f);
            float h1 = fmaxf(acc[j][1] + bias[cc + 1], 0.f);
            float h2 = fmaxf(acc[j][2] + bias[cc + 2], 0.f);
            float h3 = fmaxf(acc[j][3] + bias[cc + 3], 0.f);
            float part = h0 * u[cc + 0] + h1 * u[cc + 1] + h2 * u[cc + 2] + h3 * u[cc + 3];
            sp[(r0 + 16 * j) * 9 + (cc >> 2)] = part;
        }
    }
    __syncthreads();
    if (tid < 64) {
        long rr = row_base + tid;
        if (rr < N) {
            float t = 0.f;
            #pragma unroll
            for (int g = 0; g < 8; ++g) t += sp[tid * 9 + g];
            s_out[rr] = t;
        }
    }
}

// ---------------- GEMM for int nodes: K=64, M=32, 64-row tile, 128 threads ----------------
__global__ __launch_bounds__(128) void gemm_int(
    const float* __restrict__ X, const float* __restrict__ W,
    const float* __restrict__ bi,
    float* __restrict__ R, int N)
{
    __shared__ float xs[64 * 68];
    __shared__ float lw[64 * 32];
    const int tid = threadIdx.x;
    const long row_base = (long)blockIdx.x * 64;

    #pragma unroll
    for (int i = 0; i < 4; ++i)
        ((float4*)lw)[tid + i * 128] = ((const float4*)W)[tid + i * 128];
    #pragma unroll
    for (int i = 0; i < 8; ++i) {
        int idx = tid + i * 128;
        int r = idx >> 4, k4 = idx & 15;
        long rr = row_base + r;
        float4 val = make_float4(0.f, 0.f, 0.f, 0.f);
        if (rr < N) val = ((const float4*)X)[rr * 16 + k4];
        *(float4*)&xs[r * 68 + k4 * 4] = val;
    }
    __syncthreads();

    const int r0 = tid & 15;
    const int c0 = (tid >> 4) * 4;   // 0..28
    float acc[4][4] = {{0.f}};
    #pragma unroll 4
    for (int k = 0; k < 64; k += 4) {
        float4 xr[4];
        #pragma unroll
        for (int j = 0; j < 4; ++j)
            xr[j] = *(const float4*)&xs[(r0 + 16 * j) * 68 + k];
        #pragma unroll
        for (int kk = 0; kk < 4; ++kk) {
            float4 wv = *(const float4*)&lw[(k + kk) * 32 + c0];
            #pragma unroll
            for (int j = 0; j < 4; ++j) {
                float xv = (kk == 0) ? xr[j].x : (kk == 1) ? xr[j].y : (kk == 2) ? xr[j].z : xr[j].w;
                acc[j][0] = fmaf(xv, wv.x, acc[j][0]);
                acc[j][1] = fmaf(xv, wv.y, acc[j][1]);
                acc[j][2] = fmaf(xv, wv.z, acc[j][2]);
                acc[j][3] = fmaf(xv, wv.w, acc[j][3]);
            }
        }
    }
    #pragma unroll
    for (int j = 0; j < 4; ++j) {
        long rr = row_base + r0 + 16 * j;
        if (rr >= N) continue;
        float4 o;
        o.x = acc[j][0] + bi[c0 + 0];
        o.y = acc[j][1] + bi[c0 + 1];
        o.z = acc[j][2] + bi[c0 + 2];
        o.w = acc[j][3] + bi[c0 + 3];
        *(float4*)&R[rr * 32 + c0] = o;
    }
}

// ---------------- CSR build: histogram ----------------
__global__ __launch_bounds__(256) void hist_kernel(
    const int* __restrict__ dst_si, const int* __restrict__ dst_m,
    int* __restrict__ deg_si, int* __restrict__ deg_m)
{
    int e = blockIdx.x * 256 + threadIdx.x;
    if (e >= NEDGE) return;
    if (blockIdx.y == 0) atomicAdd(&deg_si[dst_si[e]], 1);
    else                 atomicAdd(&deg_m[dst_m[e]], 1);
}

// ---------------- CSR build: block-level exclusive scan (1024 elems/block) ----------------
__global__ __launch_bounds__(256) void scan1_kernel(
    const int* __restrict__ deg_si, const int* __restrict__ deg_m,
    int* __restrict__ rp_si, int* __restrict__ rp_m, int* __restrict__ bsum)
{
    const int rel = blockIdx.y;
    const int* deg = rel ? deg_m : deg_si;
    int* rp = rel ? rp_m : rp_si;
    __shared__ int ls[256];
    const int tid = threadIdx.x;
    const int base = blockIdx.x * 1024 + tid * 4;
    int v[4];
    #pragma unroll
    for (int j = 0; j < 4; ++j) v[j] = (base + j < NINT) ? deg[base + j] : 0;
    int tsum = v[0] + v[1] + v[2] + v[3];
    ls[tid] = tsum;
    __syncthreads();
    for (int off = 1; off < 256; off <<= 1) {
        int t = (tid >= off) ? ls[tid - off] : 0;
        __syncthreads();
        ls[tid] += t;
        __syncthreads();
    }
    int run = ls[tid] - tsum;
    #pragma unroll
    for (int j = 0; j < 4; ++j) {
        if (base + j < NINT) rp[base + j] = run;
        run += v[j];
    }
    if (tid == 255) bsum[rel * 512 + blockIdx.x] = ls[255];
}

// ---------------- CSR build: scan of block sums ----------------
__global__ __launch_bounds__(512) void scan2_kernel(int* __restrict__ bsum)
{
    int* bs = bsum + blockIdx.y * 512;
    __shared__ int ls[512];
    const int tid = threadIdx.x;
    int v = (tid < NB_SCAN) ? bs[tid] : 0;
    ls[tid] = v;
    __syncthreads();
    for (int off = 1; off < 512; off <<= 1) {
        int t = (tid >= off) ? ls[tid - off] : 0;
        __syncthreads();
        ls[tid] += t;
        __syncthreads();
    }
    bs[tid] = ls[tid] - v;   // exclusive
}

// ---------------- CSR build: add block offsets ----------------
__global__ __launch_bounds__(256) void scan3_kernel(
    int* __restrict__ rp_si, int* __restrict__ rp_m, const int* __restrict__ bsum)
{
    int i = blockIdx.x * 256 + threadIdx.x;
    if (i >= NINT) return;
    int rel = blockIdx.y;
    int* rp = rel ? rp_m : rp_si;
    rp[i] += bsum[rel * 512 + (i >> 10)];
}

// ---------------- CSR build: bucket fill (deg doubles as down-counting cursor) ----------------
__global__ __launch_bounds__(256) void fill_kernel(
    const int* __restrict__ src_si, const int* __restrict__ dst_si,
    const int* __restrict__ src_m,  const int* __restrict__ dst_m,
    const int* __restrict__ rp_si,  const int* __restrict__ rp_m,
    int* __restrict__ deg_si, int* __restrict__ deg_m,
    int* __restrict__ ei_si,  int* __restrict__ ei_m)
{
    int e = blockIdx.x * 256 + threadIdx.x;
    if (e >= NEDGE) return;
    if (blockIdx.y == 0) {
        int dn = dst_si[e], sn = src_si[e];
        int old = atomicSub(&deg_si[dn], 1);
        ei_si[rp_si[dn] + old - 1] = sn;
    } else {
        int dn = dst_m[e], sn = src_m[e];
        int old = atomicSub(&deg_m[dn], 1);
        ei_m[rp_m[dn] + old - 1] = sn;
    }
}

// ---------------- gather epilogue: 4 features/lane, 8 lanes/node ----------------
__global__ __launch_bounds__(256) void final_gather(
    const float* __restrict__ r_int,
    const float* __restrict__ p_si, const float* __restrict__ p_m,
    const float* __restrict__ s_si, const float* __restrict__ s_m,
    const int* __restrict__ rp_si, const int* __restrict__ ei_si,
    const int* __restrict__ rp_m,  const int* __restrict__ ei_m,
    const float* __restrict__ v, const float* __restrict__ c0,
    float* __restrict__ out)
{
    long gid = (long)blockIdx.x * 256 + threadIdx.x;
    long node = gid >> 3;
    int f4 = threadIdx.x & 7;          // feature quad: covers features f4*4 .. f4*4+3
    if (node >= NINT) return;

    // level 0: independent loads
    int rs  = rp_si[node], res = rp_si[node + 1];
    int rm  = rp_m[node],  rem = rp_m[node + 1];
    float4 r  = ((const float4*)r_int)[node * 8 + f4];
    float4 vf = ((const float4*)v)[f4];
    int ds = res - rs, dm = rem - rm;

    // level 1: first-edge indices (safe index 0 when empty)
    int sn_s = (ds > 0) ? ei_si[rs] : 0;
    int sn_m = (dm > 0) ? ei_m[rm] : 0;

    // level 2: both relations' gathers in flight
    float4 ps = ((const float4*)p_si)[(long)sn_s * 8 + f4];
    float4 pm = ((const float4*)p_m)[(long)sn_m * 8 + f4];
    float qs = s_si[sn_s];
    float qm = s_m[sn_m];

    float msk_s = (ds > 0) ? 1.f : 0.f;
    float msk_m = (dm > 0) ? 1.f : 0.f;
    float4 a_si = make_float4(msk_s * ps.x, msk_s * ps.y, msk_s * ps.z, msk_s * ps.w);
    float4 a_m  = make_float4(msk_m * pm.x, msk_m * pm.y, msk_m * pm.z, msk_m * pm.w);
    float ss_si = msk_s * qs;
    float ss_m  = msk_m * qm;

    // tail: deg >= 2
    for (int e = 1; e < ds; ++e) {
        int sn = ei_si[rs + e];
        float4 p = ((const float4*)p_si)[(long)sn * 8 + f4];
        a_si.x += p.x; a_si.y += p.y; a_si.z += p.z; a_si.w += p.w;
        ss_si += s_si[sn];
    }
    for (int e = 1; e < dm; ++e) {
        int sn = ei_m[rm + e];
        float4 p = ((const float4*)p_m)[(long)sn * 8 + f4];
        a_m.x += p.x; a_m.y += p.y; a_m.z += p.z; a_m.w += p.w;
        ss_m += s_m[sn];
    }

    float wsc = 0.5f / fmaxf((float)ds, 1.0f);
    float wmc = 0.5f / fmaxf((float)dm, 1.0f);

    float h0 = fmaxf(r.x + wsc * a_si.x + wmc * a_m.x, 0.f);
    float h1 = fmaxf(r.y + wsc * a_si.y + wmc * a_m.y, 0.f);
    float h2 = fmaxf(r.z + wsc * a_si.z + wmc * a_m.z, 0.f);
    float h3 = fmaxf(r.w + wsc * a_si.w + wmc * a_m.w, 0.f);
    float t = h0 * vf.x + h1 * vf.y + h2 * vf.z + h3 * vf.w;
    t += __shfl_xor(t, 1);
    t += __shfl_xor(t, 2);
    t += __shfl_xor(t, 4);
    if (f4 == 0)
        out[node] = t + wsc * ss_si + wmc * ss_m + c0[0];
}

extern "C" void kernel_launch(void* const* d_in, const int* in_sizes, int n_in,
                              void* d_out, int out_size, void* d_ws, size_t ws_size,
                              hipStream_t stream)
{
    const float* x_si     = (const float*)d_in[0];
    const float* x_m      = (const float*)d_in[1];
    const float* x_int    = (const float*)d_in[2];
    const float* W1l_si2i = (const float*)d_in[3];
    const float* W1r_si2i = (const float*)d_in[4];
    const float* b1_si2i  = (const float*)d_in[5];
    const float* W1l_m2i  = (const float*)d_in[6];
    const float* W1r_m2i  = (const float*)d_in[7];
    const float* b1_m2i   = (const float*)d_in[8];
    const float* W1l_si   = (const float*)d_in[9];
    const float* W1r_si   = (const float*)d_in[10];
    const float* b1_si    = (const float*)d_in[11];
    const float* W1l_m    = (const float*)d_in[12];
    const float* W1r_m    = (const float*)d_in[13];
    const float* b1_m     = (const float*)d_in[14];
    const float* W2l_si2i = (const float*)d_in[15];
    const float* W2r_si2i = (const float*)d_in[16];
    const float* b2_si2i  = (const float*)d_in[17];
    const float* W2l_m2i  = (const float*)d_in[18];
    const float* W2r_m2i  = (const float*)d_in[19];
    const float* b2_m2i   = (const float*)d_in[20];
    // d_in[21..26] unused (don't reach the readout)
    const float* Wlin     = (const float*)d_in[27];
    const float* blin     = (const float*)d_in[28];
    const int* src_si2i   = (const int*)d_in[29];
    const int* dst_si2i   = (const int*)d_in[30];
    const int* src_m2i    = (const int*)d_in[31];
    const int* dst_m2i    = (const int*)d_in[32];

    float* ws = (float*)d_ws;
    if (ws_size < (size_t)OFF_END * sizeof(float)) return;

    int* deg_si = (int*)(ws + OFF_DEG);
    int* deg_m  = deg_si + 500000;
    int* rp_si  = (int*)(ws + OFF_RP);
    int* rp_m   = rp_si + 500032;
    int* ei_si  = (int*)(ws + OFF_EI);
    int* ei_m   = ei_si + 500000;
    int* bsum   = (int*)(ws + OFF_BS);

    prep_kernel<<<1, 256, 0, stream>>>(
        W1l_si2i, W1l_si, W1r_si, W1l_m2i, W1l_m, W1r_m,
        W1r_si2i, W1r_m2i, b1_si2i, b1_m2i,
        W2l_si2i, W2l_m2i, W2r_si2i, W2r_m2i,
        b2_si2i, b2_m2i, Wlin, blin,
        ws + OFF_WSI, ws + OFF_WM, ws + OFF_WI, ws + OFF_BI,
        ws + OFF_USI, ws + OFF_UM, ws + OFF_V, ws + OFF_C0,
        rp_si, rp_m);

    // zero deg (4 MB)
    hipMemsetAsync(deg_si, 0, 1000000 * sizeof(int), stream);

    // CSR build for both relations
    dim3 egrid((NEDGE + 255) / 256, 2);
    hist_kernel<<<egrid, 256, 0, stream>>>(dst_si2i, dst_m2i, deg_si, deg_m);
    scan1_kernel<<<dim3(NB_SCAN, 2), 256, 0, stream>>>(deg_si, deg_m, rp_si, rp_m, bsum);
    scan2_kernel<<<dim3(1, 2), 512, 0, stream>>>(bsum);
    scan3_kernel<<<dim3((NINT + 255) / 256, 2), 256, 0, stream>>>(rp_si, rp_m, bsum);
    fill_kernel<<<egrid, 256, 0, stream>>>(src_si2i, dst_si2i, src_m2i, dst_m2i,
                                           rp_si, rp_m, deg_si, deg_m, ei_si, ei_m);

    // layer-1 projections (s fused into gemm_src epilogue; H never materialized)
    gemm_src<<<(NSI + 63) / 64, 256, 0, stream>>>(x_si, ws + OFF_WSI, b1_si, ws + OFF_USI,
                                                  ws + OFF_PSI, ws + OFF_SSI, NSI);
    gemm_src<<<(NM  + 63) / 64, 256, 0, stream>>>(x_m,  ws + OFF_WM,  b1_m,  ws + OFF_UM,
                                                  ws + OFF_PM,  ws + OFF_SM,  NM);
    gemm_int<<<(NINT + 63) / 64, 128, 0, stream>>>(x_int, ws + OFF_WI, ws + OFF_BI, ws + OFF_RI, NINT);

    // gather-mean + layer2 + readout (4 features per lane)
    final_gather<<<(NINT * 8) / 256, 256, 0, stream>>>(ws + OFF_RI,
                                                       ws + OFF_PSI, ws + OFF_PM,
                                                       ws + OFF_SSI, ws + OFF_SM,
                                                       rp_si, ei_si,
                                                       rp_m,  ei_m,
                                                       ws + OFF_V, ws + OFF_C0, (float*)d_out);
}